// Round 1
// baseline (197.258 us; speedup 1.0000x reference)
//
#include <hip/hip_runtime.h>
#include <hip/hip_bf16.h>

// MoE MLP (top-2 of 8 experts), T=4096 tokens, D=1024, W=1024.
// R7: (1) GEMM tile 128x64 -> 128x128 (m97 structure, 65.5 FLOP/LDS-byte,
//         grid 768 = 3 blocks/CU, acc[4][4], same proven granule-XOR swizzle).
//     (2) build_lists kernel removed: router waves build per-expert lists via
//         2 global atomicAdds/token on 64B-padded counters (memset-zeroed).
//     (3) w2 transpose moved out of pre into gemm1's grid (blocks >= 768):
//         its BW-bound traffic overlaps gemm1's compute-bound phase.
// Retained: XCD map (expert = bid&7), fused w1-transpose+router pre, CAP=1536,
//           BK=64 (2 MFMA halves per barrier pair), gload_lds width-16 staging.

#define T_TOKENS 4096
#define DD 1024
#define EE 8
#define WW 1024
#define CAP 1536              // per-expert capacity (expected ~1024, sigma ~28)
#define BM 128
#define BN 128
#define BK 64
#define MT (CAP / BM)         // 12 m-tiles max per expert
#define NT (WW / BN)          // 8 n-tiles
#define GEMM_BLOCKS (EE * MT * NT)  // 768
#define TR1_BLOCKS 2048       // w1 transpose blocks (in pre)
#define TR2_BLOCKS 2048       // w2 transpose blocks (fused into gemm1)

typedef short bf16x8 __attribute__((ext_vector_type(8)));
typedef float f32x4 __attribute__((ext_vector_type(4)));

__device__ __forceinline__ void gload_lds16(const void* g, void* l) {
  __builtin_amdgcn_global_load_lds((__attribute__((address_space(1))) void*)(g),
                                   (__attribute__((address_space(3))) void*)(l),
                                   16, 0, 0);
}

__device__ __forceinline__ float bf2f(unsigned short u) {
  union { unsigned int i; float f; } v; v.i = (unsigned int)u << 16; return v.f;
}

// ---------------- pre: w1 transpose + router (+ list build via atomics) ----------------
// blocks [0,2048): w1 transpose; [2048,3072): router, 1 wave = 1 token.
__global__ __launch_bounds__(256) void pre_kernel(
    const float* __restrict__ w1, const float* __restrict__ x,
    const float* __restrict__ rw,
    __hip_bfloat16* __restrict__ w1t, __hip_bfloat16* __restrict__ xb,
    int* __restrict__ counts, int* __restrict__ idx,
    int* __restrict__ tslot, float* __restrict__ wpair)
{
  __shared__ float tile[64][65];
  int b = blockIdx.x;
  if (b < TR1_BLOCKS) {
    // w1 [D=1024, E*W=8192] -> w1t [8192, 1024] bf16
    int bx = b & 15;            // dst col tile (16 tiles of 64 over 1024)
    int by = b >> 4;            // 0..127 -> dst rows 0..8191
    const float* src = w1;
    __hip_bfloat16* dst = w1t;
    long src_ld = EE * WW, dst_ld = DD;
    long c0 = (long)bx * 64;    // dst col = src row
    long r0 = (long)by * 64;    // dst row = src col
    int tx = threadIdx.x & 15, ty = threadIdx.x >> 4;
#pragma unroll
    for (int i = 0; i < 4; i++) {
      int sr = ty + 16 * i;
      f32x4 v = *(const f32x4*)(src + (c0 + sr) * src_ld + r0 + tx * 4);
      tile[sr][tx * 4 + 0] = v[0];
      tile[sr][tx * 4 + 1] = v[1];
      tile[sr][tx * 4 + 2] = v[2];
      tile[sr][tx * 4 + 3] = v[3];
    }
    __syncthreads();
#pragma unroll
    for (int i = 0; i < 4; i++) {
      int dr = ty + 16 * i;
      union { __hip_bfloat16 hb[4]; ushort4 u4; } pk;
#pragma unroll
      for (int j = 0; j < 4; j++)
        pk.hb[j] = __float2bfloat16(tile[tx * 4 + j][dr]);
      *(ushort4*)((unsigned short*)dst + (r0 + dr) * dst_ld + c0 + tx * 4) = pk.u4;
    }
  } else {
    // router: one wave per token, fp32 logits, top-2, lists via global atomics
    int lane = threadIdx.x & 63;
    int wave = threadIdx.x >> 6;
    int t = (b - TR1_BLOCKS) * 4 + wave;
    const float* xrow = x + (size_t)t * DD;
    float acc[EE];
#pragma unroll
    for (int e = 0; e < EE; e++) acc[e] = 0.f;
#pragma unroll
    for (int i = 0; i < DD / 64; i++) {
      int d = lane + i * 64;
      float xv = xrow[d];
      xb[t * DD + d] = __float2bfloat16(xv);   // fused x -> bf16
#pragma unroll
      for (int e = 0; e < EE; e++) acc[e] += xv * rw[e * DD + d];
    }
#pragma unroll
    for (int e = 0; e < EE; e++) {
#pragma unroll
      for (int off = 32; off > 0; off >>= 1)
        acc[e] += __shfl_down(acc[e], off, 64);
    }
    if (lane == 0) {
      float p[EE];
#pragma unroll
      for (int e = 0; e < EE; e++) p[e] = 1.f / (1.f + expf(-acc[e]));
      // top-2, ties -> lowest index (matches jax.lax.top_k stable ordering)
      int e0 = 0; float b0 = p[0];
      for (int e = 1; e < EE; e++) if (p[e] > b0) { b0 = p[e]; e0 = e; }
      int e1 = -1; float b1 = -1.f;
      for (int e = 0; e < EE; e++) {
        if (e == e0) continue;
        if (p[e] > b1) { b1 = p[e]; e1 = e; }
      }
      float s = b0 + b1 + 1e-20f;
      // slot assignment order is arbitrary -> atomics are fine (combine uses tslot)
      int s0 = atomicAdd(&counts[e0 * 16], 1);
      int s1 = atomicAdd(&counts[e1 * 16], 1);
      int p0 = e0 * CAP + s0, p1 = e1 * CAP + s1;
      idx[p0] = t; idx[p1] = t;
      tslot[2 * t] = p0; tslot[2 * t + 1] = p1;
      wpair[2 * t]     = b0 / s;
      wpair[2 * t + 1] = b1 / s;
    }
  }
}

// ---------------- grouped GEMM1 (+ fused w2 transpose blocks) ----------------
// blocks [0,768): h = gather(xb) @ W1_e, act = relu(h)^2, 128x128 tile, BK=64.
// blocks [768, 768+2048): w2 [E*W,D] -> w2t[e] [D,W] bf16 (only gemm2 needs it).
// XCD map: expert = bid & 7 (round-robin dispatch puts expert e on XCD e;
// per-expert B slab 2MB + A subset ~2MB stay L2-resident).
__global__ __launch_bounds__(256, 3) void gemm1_kernel(
    const __hip_bfloat16* __restrict__ xb, const __hip_bfloat16* __restrict__ w1t,
    const int* __restrict__ counts, const int* __restrict__ idx,
    __hip_bfloat16* __restrict__ act,
    const float* __restrict__ w2, __hip_bfloat16* __restrict__ w2t)
{
  __shared__ __attribute__((aligned(16))) char smem[32768];  // As 16K | Bs 16K
  int bid = blockIdx.x;
  if (bid >= GEMM_BLOCKS) {
    // ---- w2 transpose: tile[64][65] fp32 aliased onto smem (16640 B) ----
    float (*tile)[65] = (float (*)[65])smem;
    int b2 = bid - GEMM_BLOCKS;
    int bx = b2 & 15;           // dst col tile over W
    int z = b2 >> 4;            // 0..127
    int e = z >> 4, yy = z & 15;
    const float* src = w2 + (long)e * WW * DD;
    __hip_bfloat16* dst = w2t + (long)e * DD * WW;
    long src_ld = DD, dst_ld = WW;
    long c0 = (long)bx * 64;    // dst col = src row (W dim)
    long r0 = (long)yy * 64;    // dst row = src col (D dim)
    int tx = threadIdx.x & 15, ty = threadIdx.x >> 4;
#pragma unroll
    for (int i = 0; i < 4; i++) {
      int sr = ty + 16 * i;
      f32x4 v = *(const f32x4*)(src + (c0 + sr) * src_ld + r0 + tx * 4);
      tile[sr][tx * 4 + 0] = v[0];
      tile[sr][tx * 4 + 1] = v[1];
      tile[sr][tx * 4 + 2] = v[2];
      tile[sr][tx * 4 + 3] = v[3];
    }
    __syncthreads();
#pragma unroll
    for (int i = 0; i < 4; i++) {
      int dr = ty + 16 * i;
      union { __hip_bfloat16 hb[4]; ushort4 u4; } pk;
#pragma unroll
      for (int j = 0; j < 4; j++)
        pk.hb[j] = __float2bfloat16(tile[tx * 4 + j][dr]);
      *(ushort4*)((unsigned short*)dst + (r0 + dr) * dst_ld + c0 + tx * 4) = pk.u4;
    }
    return;
  }
  short* As = (short*)smem;
  short* Bs = (short*)(smem + 16384);
  int e = bid & 7;
  int i = bid >> 3;
  int mt = i >> 3, nt = i & 7;
  int n_e = counts[e * 16];
  if (mt * BM >= n_e) return;

  int tid = threadIdx.x;
  int lane = tid & 63;
  int wave = __builtin_amdgcn_readfirstlane(tid >> 6);
  int wm = (wave >> 1) * 64, wn = (wave & 1) * 64;
  int m16 = lane & 15, qd = lane >> 4;

  // staging: granule = 16B (8 bf16); 8 granule-cols/row; slot s -> row s>>3,
  // swizzled col (s&7)^(r&7); LDS dest linear (gload_lds is base+lane*16).
  const __hip_bfloat16* gA[4];
  const __hip_bfloat16* gB[4];
#pragma unroll
  for (int i2 = 0; i2 < 4; i2++) {
    int s = i2 * 256 + tid;
    int r = s >> 3;
    int q = (s & 7) ^ (r & 7);
    int rowA = mt * BM + r;
    int slot = rowA < n_e ? rowA : n_e - 1;   // clamp tail rows to valid slot
    int tok = idx[e * CAP + slot];
    gA[i2] = xb + (size_t)tok * DD + q * 8;
    gB[i2] = w1t + ((size_t)e * WW + nt * BN + r) * DD + q * 8;
  }
  short* ldsA[4];
  short* ldsB[4];
#pragma unroll
  for (int i2 = 0; i2 < 4; i2++) {
    ldsA[i2] = As + (i2 * 256 + wave * 64) * 8;
    ldsB[i2] = Bs + (i2 * 256 + wave * 64) * 8;
  }

  int aoff[4][2], boff[4][2];
#pragma unroll
  for (int mi = 0; mi < 4; mi++) {
    int r = wm + mi * 16 + m16;
#pragma unroll
    for (int h = 0; h < 2; h++)
      aoff[mi][h] = (r * 8 + ((qd + h * 4) ^ (r & 7))) * 8;
  }
#pragma unroll
  for (int ni = 0; ni < 4; ni++) {
    int r = wn + ni * 16 + m16;
#pragma unroll
    for (int h = 0; h < 2; h++)
      boff[ni][h] = (r * 8 + ((qd + h * 4) ^ (r & 7))) * 8;
  }

  f32x4 zero = {0.f, 0.f, 0.f, 0.f};
  f32x4 acc[4][4];
#pragma unroll
  for (int mi = 0; mi < 4; mi++)
#pragma unroll
    for (int ni = 0; ni < 4; ni++) acc[mi][ni] = zero;

  for (int k0 = 0; k0 < DD; k0 += BK) {
#pragma unroll
    for (int i2 = 0; i2 < 4; i2++) gload_lds16(gA[i2] + k0, ldsA[i2]);
#pragma unroll
    for (int i2 = 0; i2 < 4; i2++) gload_lds16(gB[i2] + k0, ldsB[i2]);
    __syncthreads();
#pragma unroll
    for (int h = 0; h < 2; h++) {
      bf16x8 af[4], bfr[4];
#pragma unroll
      for (int mi = 0; mi < 4; mi++) af[mi] = *(const bf16x8*)(As + aoff[mi][h]);
#pragma unroll
      for (int ni = 0; ni < 4; ni++) bfr[ni] = *(const bf16x8*)(Bs + boff[ni][h]);
#pragma unroll
      for (int mi = 0; mi < 4; mi++)
#pragma unroll
        for (int ni = 0; ni < 4; ni++)
          acc[mi][ni] = __builtin_amdgcn_mfma_f32_16x16x32_bf16(
              af[mi], bfr[ni], acc[mi][ni], 0, 0, 0);
    }
    __syncthreads();
  }

  // epilogue: relu^2 -> bf16 act[(e*CAP + slot)][col]
#pragma unroll
  for (int mi = 0; mi < 4; mi++) {
#pragma unroll
    for (int reg = 0; reg < 4; reg++) {
      int rowt = mt * BM + wm + mi * 16 + qd * 4 + reg;
      if (rowt < n_e) {
#pragma unroll
        for (int ni = 0; ni < 4; ni++) {
          float v = acc[mi][ni][reg];
          v = v > 0.f ? v * v : 0.f;
          int col = nt * BN + wn + ni * 16 + m16;
          act[((size_t)e * CAP + rowt) * WW + col] = __float2bfloat16(v);
        }
      }
    }
  }
}

// ---------------- grouped GEMM2: y = act @ W2_e (raw bf16 y, no atomics) ----------------
__global__ __launch_bounds__(256, 3) void gemm2_kernel(
    const __hip_bfloat16* __restrict__ act, const __hip_bfloat16* __restrict__ w2t,
    const int* __restrict__ counts, __hip_bfloat16* __restrict__ y)
{
  __shared__ __attribute__((aligned(16))) char smem[32768];
  short* As = (short*)smem;
  short* Bs = (short*)(smem + 16384);
  int bid = blockIdx.x;
  int e = bid & 7;
  int i = bid >> 3;
  int mt = i >> 3, nt = i & 7;
  int n_e = counts[e * 16];
  if (mt * BM >= n_e) return;

  int tid = threadIdx.x;
  int lane = tid & 63;
  int wave = __builtin_amdgcn_readfirstlane(tid >> 6);
  int wm = (wave >> 1) * 64, wn = (wave & 1) * 64;
  int m16 = lane & 15, qd = lane >> 4;

  const __hip_bfloat16* gA[4];
  const __hip_bfloat16* gB[4];
#pragma unroll
  for (int i2 = 0; i2 < 4; i2++) {
    int s = i2 * 256 + tid;
    int r = s >> 3;
    int q = (s & 7) ^ (r & 7);
    // rows >= n_e: poison bytes, but row-isolated in MFMA -> discarded rows only
    gA[i2] = act + ((size_t)e * CAP + mt * BM + r) * WW + q * 8;
    gB[i2] = w2t + ((size_t)e * DD + nt * BN + r) * WW + q * 8;
  }
  short* ldsA[4];
  short* ldsB[4];
#pragma unroll
  for (int i2 = 0; i2 < 4; i2++) {
    ldsA[i2] = As + (i2 * 256 + wave * 64) * 8;
    ldsB[i2] = Bs + (i2 * 256 + wave * 64) * 8;
  }

  int aoff[4][2], boff[4][2];
#pragma unroll
  for (int mi = 0; mi < 4; mi++) {
    int r = wm + mi * 16 + m16;
#pragma unroll
    for (int h = 0; h < 2; h++)
      aoff[mi][h] = (r * 8 + ((qd + h * 4) ^ (r & 7))) * 8;
  }
#pragma unroll
  for (int ni = 0; ni < 4; ni++) {
    int r = wn + ni * 16 + m16;
#pragma unroll
    for (int h = 0; h < 2; h++)
      boff[ni][h] = (r * 8 + ((qd + h * 4) ^ (r & 7))) * 8;
  }

  f32x4 zero = {0.f, 0.f, 0.f, 0.f};
  f32x4 acc[4][4];
#pragma unroll
  for (int mi = 0; mi < 4; mi++)
#pragma unroll
    for (int ni = 0; ni < 4; ni++) acc[mi][ni] = zero;

  for (int k0 = 0; k0 < WW; k0 += BK) {
#pragma unroll
    for (int i2 = 0; i2 < 4; i2++) gload_lds16(gA[i2] + k0, ldsA[i2]);
#pragma unroll
    for (int i2 = 0; i2 < 4; i2++) gload_lds16(gB[i2] + k0, ldsB[i2]);
    __syncthreads();
#pragma unroll
    for (int h = 0; h < 2; h++) {
      bf16x8 af[4], bfr[4];
#pragma unroll
      for (int mi = 0; mi < 4; mi++) af[mi] = *(const bf16x8*)(As + aoff[mi][h]);
#pragma unroll
      for (int ni = 0; ni < 4; ni++) bfr[ni] = *(const bf16x8*)(Bs + boff[ni][h]);
#pragma unroll
      for (int mi = 0; mi < 4; mi++)
#pragma unroll
        for (int ni = 0; ni < 4; ni++)
          acc[mi][ni] = __builtin_amdgcn_mfma_f32_16x16x32_bf16(
              af[mi], bfr[ni], acc[mi][ni], 0, 0, 0);
    }
    __syncthreads();
  }

  // epilogue: raw y (routing weights applied in combine)
#pragma unroll
  for (int mi = 0; mi < 4; mi++) {
#pragma unroll
    for (int reg = 0; reg < 4; reg++) {
      int slot = mt * BM + wm + mi * 16 + qd * 4 + reg;
      if (slot < n_e) {
#pragma unroll
        for (int ni = 0; ni < 4; ni++) {
          int col = nt * BN + wn + ni * 16 + m16;
          y[((size_t)e * CAP + slot) * DD + col] = __float2bfloat16(acc[mi][ni][reg]);
        }
      }
    }
  }
}

// ---------------- combine: out[t] = w0*y[slot0] + w1*y[slot1] ----------------
__global__ __launch_bounds__(256) void combine_kernel(
    const __hip_bfloat16* __restrict__ y, const int* __restrict__ tslot,
    const float* __restrict__ wpair, float* __restrict__ out)
{
  int t = blockIdx.x;
  int c = threadIdx.x * 4;
  int s0 = tslot[2 * t], s1 = tslot[2 * t + 1];
  float w0 = wpair[2 * t], w1 = wpair[2 * t + 1];
  const unsigned short* yu = (const unsigned short*)y;
  ushort4 a = *(const ushort4*)(yu + (size_t)s0 * DD + c);
  ushort4 bq = *(const ushort4*)(yu + (size_t)s1 * DD + c);
  f32x4 o;
  o[0] = w0 * bf2f(a.x) + w1 * bf2f(bq.x);
  o[1] = w0 * bf2f(a.y) + w1 * bf2f(bq.y);
  o[2] = w0 * bf2f(a.z) + w1 * bf2f(bq.z);
  o[3] = w0 * bf2f(a.w) + w1 * bf2f(bq.w);
  *(f32x4*)(out + (size_t)t * DD + c) = o;
}

extern "C" void kernel_launch(void* const* d_in, const int* in_sizes, int n_in,
                              void* d_out, int out_size, void* d_ws, size_t ws_size,
                              hipStream_t stream)
{
  const float* x  = (const float*)d_in[0];
  const float* rw = (const float*)d_in[1];
  const float* w1 = (const float*)d_in[2];
  const float* w2 = (const float*)d_in[3];
  float* out = (float*)d_out;

  char* ws = (char*)d_ws;
  __hip_bfloat16* xb  = (__hip_bfloat16*)ws;  ws += (size_t)T_TOKENS * DD * 2;
  __hip_bfloat16* w1t = (__hip_bfloat16*)ws;  ws += (size_t)EE * WW * DD * 2;
  __hip_bfloat16* w2t = (__hip_bfloat16*)ws;  ws += (size_t)EE * DD * WW * 2;
  __hip_bfloat16* act = (__hip_bfloat16*)ws;  ws += (size_t)EE * CAP * WW * 2;
  __hip_bfloat16* y   = (__hip_bfloat16*)ws;  ws += (size_t)EE * CAP * DD * 2;
  int*   counts = (int*)ws;                   ws += 16 * EE * sizeof(int);
  int*   idx    = (int*)ws;                   ws += (size_t)EE * CAP * 4;
  int*   tslot  = (int*)ws;                   ws += (size_t)T_TOKENS * 8;
  float* wpair  = (float*)ws;                 ws += (size_t)T_TOKENS * 8;

  // counters must start at 0 (workspace arrives poisoned)
  hipMemsetAsync(counts, 0, 16 * EE * sizeof(int), stream);
  // pre: w1 transpose + router (+ atomic list build)
  pre_kernel<<<TR1_BLOCKS + T_TOKENS / 4, 256, 0, stream>>>(
      w1, x, rw, w1t, xb, counts, idx, tslot, wpair);
  // gemm1 + fused w2 transpose (w2t only needed by gemm2)
  gemm1_kernel<<<GEMM_BLOCKS + TR2_BLOCKS, 256, 0, stream>>>(
      xb, w1t, counts, idx, act, w2, w2t);
  gemm2_kernel<<<GEMM_BLOCKS, 256, 0, stream>>>(act, w2t, counts, y);
  combine_kernel<<<T_TOKENS, 256, 0, stream>>>(y, tslot, wpair, out);
}

// Round 2
// 189.528 us; speedup vs baseline: 1.0408x; 1.0408x over previous
//
#include <hip/hip_runtime.h>
#include <hip/hip_bf16.h>

// MoE MLP (top-2 of 8 experts), T=4096 tokens, D=1024, W=1024.
// R8: revert list-build to the ballot-based single-block kernel (R6-proven).
//     R7's per-token global atomics serialized on 8 hot cache lines and made
//     pre_kernel 41.4us @ 1.2TB/s (26% occ) -- 5x above its BW floor.
// Retained from R7: 128x128 GEMM tile (BK=64, acc[4][4], granule-XOR swizzle,
//     grid 768 = 3 blocks/CU), w2 transpose fused into gemm1's grid (overlaps
//     BW-bound transpose under compute-bound GEMM), XCD map expert = bid&7,
//     fused w1-transpose+router pre, CAP=1536, gload_lds width-16 staging.

#define T_TOKENS 4096
#define DD 1024
#define EE 8
#define WW 1024
#define CAP 1536              // per-expert capacity (expected ~1024, sigma ~28)
#define BM 128
#define BN 128
#define BK 64
#define MT (CAP / BM)         // 12 m-tiles max per expert
#define NT (WW / BN)          // 8 n-tiles
#define GEMM_BLOCKS (EE * MT * NT)  // 768
#define TR1_BLOCKS 2048       // w1 transpose blocks (in pre)
#define TR2_BLOCKS 2048       // w2 transpose blocks (fused into gemm1)

typedef short bf16x8 __attribute__((ext_vector_type(8)));
typedef float f32x4 __attribute__((ext_vector_type(4)));

__device__ __forceinline__ void gload_lds16(const void* g, void* l) {
  __builtin_amdgcn_global_load_lds((__attribute__((address_space(1))) void*)(g),
                                   (__attribute__((address_space(3))) void*)(l),
                                   16, 0, 0);
}

__device__ __forceinline__ float bf2f(unsigned short u) {
  union { unsigned int i; float f; } v; v.i = (unsigned int)u << 16; return v.f;
}

// ---------------- pre: w1 transpose + router (sel/wpair only, NO atomics) ----------------
// blocks [0,2048): w1 transpose; [2048,3072): router, 1 wave = 1 token.
__global__ __launch_bounds__(256) void pre_kernel(
    const float* __restrict__ w1, const float* __restrict__ x,
    const float* __restrict__ rw,
    __hip_bfloat16* __restrict__ w1t, __hip_bfloat16* __restrict__ xb,
    int* __restrict__ sel, float* __restrict__ wpair)
{
  __shared__ float tile[64][65];
  int b = blockIdx.x;
  if (b < TR1_BLOCKS) {
    // w1 [D=1024, E*W=8192] -> w1t [8192, 1024] bf16
    int bx = b & 15;            // dst col tile (16 tiles of 64 over 1024)
    int by = b >> 4;            // 0..127 -> dst rows 0..8191
    const float* src = w1;
    __hip_bfloat16* dst = w1t;
    long src_ld = EE * WW, dst_ld = DD;
    long c0 = (long)bx * 64;    // dst col = src row
    long r0 = (long)by * 64;    // dst row = src col
    int tx = threadIdx.x & 15, ty = threadIdx.x >> 4;
#pragma unroll
    for (int i = 0; i < 4; i++) {
      int sr = ty + 16 * i;
      f32x4 v = *(const f32x4*)(src + (c0 + sr) * src_ld + r0 + tx * 4);
      tile[sr][tx * 4 + 0] = v[0];
      tile[sr][tx * 4 + 1] = v[1];
      tile[sr][tx * 4 + 2] = v[2];
      tile[sr][tx * 4 + 3] = v[3];
    }
    __syncthreads();
#pragma unroll
    for (int i = 0; i < 4; i++) {
      int dr = ty + 16 * i;
      union { __hip_bfloat16 hb[4]; ushort4 u4; } pk;
#pragma unroll
      for (int j = 0; j < 4; j++)
        pk.hb[j] = __float2bfloat16(tile[tx * 4 + j][dr]);
      *(ushort4*)((unsigned short*)dst + (r0 + dr) * dst_ld + c0 + tx * 4) = pk.u4;
    }
  } else {
    // router: one wave per token, fp32 logits, top-2, no atomics
    int lane = threadIdx.x & 63;
    int wave = threadIdx.x >> 6;
    int t = (b - TR1_BLOCKS) * 4 + wave;
    const float* xrow = x + (size_t)t * DD;
    float acc[EE];
#pragma unroll
    for (int e = 0; e < EE; e++) acc[e] = 0.f;
#pragma unroll
    for (int i = 0; i < DD / 64; i++) {
      int d = lane + i * 64;
      float xv = xrow[d];
      xb[t * DD + d] = __float2bfloat16(xv);   // fused x -> bf16
#pragma unroll
      for (int e = 0; e < EE; e++) acc[e] += xv * rw[e * DD + d];
    }
#pragma unroll
    for (int e = 0; e < EE; e++) {
#pragma unroll
      for (int off = 32; off > 0; off >>= 1)
        acc[e] += __shfl_down(acc[e], off, 64);
    }
    if (lane == 0) {
      float p[EE];
#pragma unroll
      for (int e = 0; e < EE; e++) p[e] = 1.f / (1.f + expf(-acc[e]));
      // top-2, ties -> lowest index (matches jax.lax.top_k stable ordering)
      int e0 = 0; float b0 = p[0];
      for (int e = 1; e < EE; e++) if (p[e] > b0) { b0 = p[e]; e0 = e; }
      int e1 = -1; float b1 = -1.f;
      for (int e = 0; e < EE; e++) {
        if (e == e0) continue;
        if (p[e] > b1) { b1 = p[e]; e1 = e; }
      }
      float s = b0 + b1 + 1e-20f;
      sel[t] = e0 | (e1 << 8);
      wpair[2 * t]     = b0 / s;
      wpair[2 * t + 1] = b1 / s;
    }
  }
}

// ---------------- build per-expert token lists (1 block, wave-ballot agg) ----------------
__global__ __launch_bounds__(1024) void build_lists(
    const int* __restrict__ sel, int* __restrict__ counts,
    int* __restrict__ idx, int* __restrict__ tslot)
{
  __shared__ int lcnt[EE];
  int tid = threadIdx.x, lane = tid & 63;
  if (tid < EE) lcnt[tid] = 0;
  __syncthreads();
  unsigned long long lower = (1ull << lane) - 1;
#pragma unroll
  for (int j = 0; j < T_TOKENS / 1024; j++) {
    int t = j * 1024 + tid;
    int s = sel[t];
    int e0 = s & 0xff, e1 = (s >> 8) & 0xff;
    int slot0 = 0, slot1 = 0;
#pragma unroll
    for (int e = 0; e < EE; e++) {
      unsigned long long m0 = __ballot(e0 == e);
      unsigned long long m1 = __ballot(e1 == e);
      int c0 = __popcll(m0), c1 = __popcll(m1);
      int base = 0;
      if (lane == 0 && (c0 + c1) > 0) base = atomicAdd(&lcnt[e], c0 + c1);
      base = __shfl(base, 0, 64);
      if (e0 == e) slot0 = base + __popcll(m0 & lower);
      if (e1 == e) slot1 = base + c0 + __popcll(m1 & lower);
    }
    int p0 = e0 * CAP + slot0, p1 = e1 * CAP + slot1;
    idx[p0] = t; idx[p1] = t;
    tslot[2 * t] = p0; tslot[2 * t + 1] = p1;
  }
  __syncthreads();
  if (tid < EE) counts[tid] = lcnt[tid];
}

// ---------------- grouped GEMM1 (+ fused w2 transpose blocks) ----------------
// blocks [0,768): h = gather(xb) @ W1_e, act = relu(h)^2, 128x128 tile, BK=64.
// blocks [768, 768+2048): w2 [E*W,D] -> w2t[e] [D,W] bf16 (only gemm2 needs it).
// XCD map: expert = bid & 7 (round-robin dispatch puts expert e on XCD e;
// per-expert B slab 2MB + A subset ~2MB stay L2-resident).
__global__ __launch_bounds__(256, 3) void gemm1_kernel(
    const __hip_bfloat16* __restrict__ xb, const __hip_bfloat16* __restrict__ w1t,
    const int* __restrict__ counts, const int* __restrict__ idx,
    __hip_bfloat16* __restrict__ act,
    const float* __restrict__ w2, __hip_bfloat16* __restrict__ w2t)
{
  __shared__ __attribute__((aligned(16))) char smem[32768];  // As 16K | Bs 16K
  int bid = blockIdx.x;
  if (bid >= GEMM_BLOCKS) {
    // ---- w2 transpose: tile[64][65] fp32 aliased onto smem (16640 B) ----
    float (*tile)[65] = (float (*)[65])smem;
    int b2 = bid - GEMM_BLOCKS;
    int bx = b2 & 15;           // dst col tile over W
    int z = b2 >> 4;            // 0..127
    int e = z >> 4, yy = z & 15;
    const float* src = w2 + (long)e * WW * DD;
    __hip_bfloat16* dst = w2t + (long)e * DD * WW;
    long src_ld = DD, dst_ld = WW;
    long c0 = (long)bx * 64;    // dst col = src row (W dim)
    long r0 = (long)yy * 64;    // dst row = src col (D dim)
    int tx = threadIdx.x & 15, ty = threadIdx.x >> 4;
#pragma unroll
    for (int i = 0; i < 4; i++) {
      int sr = ty + 16 * i;
      f32x4 v = *(const f32x4*)(src + (c0 + sr) * src_ld + r0 + tx * 4);
      tile[sr][tx * 4 + 0] = v[0];
      tile[sr][tx * 4 + 1] = v[1];
      tile[sr][tx * 4 + 2] = v[2];
      tile[sr][tx * 4 + 3] = v[3];
    }
    __syncthreads();
#pragma unroll
    for (int i = 0; i < 4; i++) {
      int dr = ty + 16 * i;
      union { __hip_bfloat16 hb[4]; ushort4 u4; } pk;
#pragma unroll
      for (int j = 0; j < 4; j++)
        pk.hb[j] = __float2bfloat16(tile[tx * 4 + j][dr]);
      *(ushort4*)((unsigned short*)dst + (r0 + dr) * dst_ld + c0 + tx * 4) = pk.u4;
    }
    return;
  }
  short* As = (short*)smem;
  short* Bs = (short*)(smem + 16384);
  int e = bid & 7;
  int i = bid >> 3;
  int mt = i >> 3, nt = i & 7;
  int n_e = counts[e];
  if (mt * BM >= n_e) return;

  int tid = threadIdx.x;
  int lane = tid & 63;
  int wave = __builtin_amdgcn_readfirstlane(tid >> 6);
  int wm = (wave >> 1) * 64, wn = (wave & 1) * 64;
  int m16 = lane & 15, qd = lane >> 4;

  // staging: granule = 16B (8 bf16); 8 granule-cols/row; slot s -> row s>>3,
  // swizzled col (s&7)^(r&7); LDS dest linear (gload_lds is base+lane*16).
  const __hip_bfloat16* gA[4];
  const __hip_bfloat16* gB[4];
#pragma unroll
  for (int i2 = 0; i2 < 4; i2++) {
    int s = i2 * 256 + tid;
    int r = s >> 3;
    int q = (s & 7) ^ (r & 7);
    int rowA = mt * BM + r;
    int slot = rowA < n_e ? rowA : n_e - 1;   // clamp tail rows to valid slot
    int tok = idx[e * CAP + slot];
    gA[i2] = xb + (size_t)tok * DD + q * 8;
    gB[i2] = w1t + ((size_t)e * WW + nt * BN + r) * DD + q * 8;
  }
  short* ldsA[4];
  short* ldsB[4];
#pragma unroll
  for (int i2 = 0; i2 < 4; i2++) {
    ldsA[i2] = As + (i2 * 256 + wave * 64) * 8;
    ldsB[i2] = Bs + (i2 * 256 + wave * 64) * 8;
  }

  int aoff[4][2], boff[4][2];
#pragma unroll
  for (int mi = 0; mi < 4; mi++) {
    int r = wm + mi * 16 + m16;
#pragma unroll
    for (int h = 0; h < 2; h++)
      aoff[mi][h] = (r * 8 + ((qd + h * 4) ^ (r & 7))) * 8;
  }
#pragma unroll
  for (int ni = 0; ni < 4; ni++) {
    int r = wn + ni * 16 + m16;
#pragma unroll
    for (int h = 0; h < 2; h++)
      boff[ni][h] = (r * 8 + ((qd + h * 4) ^ (r & 7))) * 8;
  }

  f32x4 zero = {0.f, 0.f, 0.f, 0.f};
  f32x4 acc[4][4];
#pragma unroll
  for (int mi = 0; mi < 4; mi++)
#pragma unroll
    for (int ni = 0; ni < 4; ni++) acc[mi][ni] = zero;

  for (int k0 = 0; k0 < DD; k0 += BK) {
#pragma unroll
    for (int i2 = 0; i2 < 4; i2++) gload_lds16(gA[i2] + k0, ldsA[i2]);
#pragma unroll
    for (int i2 = 0; i2 < 4; i2++) gload_lds16(gB[i2] + k0, ldsB[i2]);
    __syncthreads();
#pragma unroll
    for (int h = 0; h < 2; h++) {
      bf16x8 af[4], bfr[4];
#pragma unroll
      for (int mi = 0; mi < 4; mi++) af[mi] = *(const bf16x8*)(As + aoff[mi][h]);
#pragma unroll
      for (int ni = 0; ni < 4; ni++) bfr[ni] = *(const bf16x8*)(Bs + boff[ni][h]);
#pragma unroll
      for (int mi = 0; mi < 4; mi++)
#pragma unroll
        for (int ni = 0; ni < 4; ni++)
          acc[mi][ni] = __builtin_amdgcn_mfma_f32_16x16x32_bf16(
              af[mi], bfr[ni], acc[mi][ni], 0, 0, 0);
    }
    __syncthreads();
  }

  // epilogue: relu^2 -> bf16 act[(e*CAP + slot)][col]
#pragma unroll
  for (int mi = 0; mi < 4; mi++) {
#pragma unroll
    for (int reg = 0; reg < 4; reg++) {
      int rowt = mt * BM + wm + mi * 16 + qd * 4 + reg;
      if (rowt < n_e) {
#pragma unroll
        for (int ni = 0; ni < 4; ni++) {
          float v = acc[mi][ni][reg];
          v = v > 0.f ? v * v : 0.f;
          int col = nt * BN + wn + ni * 16 + m16;
          act[((size_t)e * CAP + rowt) * WW + col] = __float2bfloat16(v);
        }
      }
    }
  }
}

// ---------------- grouped GEMM2: y = act @ W2_e (raw bf16 y, no atomics) ----------------
__global__ __launch_bounds__(256, 3) void gemm2_kernel(
    const __hip_bfloat16* __restrict__ act, const __hip_bfloat16* __restrict__ w2t,
    const int* __restrict__ counts, __hip_bfloat16* __restrict__ y)
{
  __shared__ __attribute__((aligned(16))) char smem[32768];
  short* As = (short*)smem;
  short* Bs = (short*)(smem + 16384);
  int bid = blockIdx.x;
  int e = bid & 7;
  int i = bid >> 3;
  int mt = i >> 3, nt = i & 7;
  int n_e = counts[e];
  if (mt * BM >= n_e) return;

  int tid = threadIdx.x;
  int lane = tid & 63;
  int wave = __builtin_amdgcn_readfirstlane(tid >> 6);
  int wm = (wave >> 1) * 64, wn = (wave & 1) * 64;
  int m16 = lane & 15, qd = lane >> 4;

  const __hip_bfloat16* gA[4];
  const __hip_bfloat16* gB[4];
#pragma unroll
  for (int i2 = 0; i2 < 4; i2++) {
    int s = i2 * 256 + tid;
    int r = s >> 3;
    int q = (s & 7) ^ (r & 7);
    // rows >= n_e: poison bytes, but row-isolated in MFMA -> discarded rows only
    gA[i2] = act + ((size_t)e * CAP + mt * BM + r) * WW + q * 8;
    gB[i2] = w2t + ((size_t)e * DD + nt * BN + r) * WW + q * 8;
  }
  short* ldsA[4];
  short* ldsB[4];
#pragma unroll
  for (int i2 = 0; i2 < 4; i2++) {
    ldsA[i2] = As + (i2 * 256 + wave * 64) * 8;
    ldsB[i2] = Bs + (i2 * 256 + wave * 64) * 8;
  }

  int aoff[4][2], boff[4][2];
#pragma unroll
  for (int mi = 0; mi < 4; mi++) {
    int r = wm + mi * 16 + m16;
#pragma unroll
    for (int h = 0; h < 2; h++)
      aoff[mi][h] = (r * 8 + ((qd + h * 4) ^ (r & 7))) * 8;
  }
#pragma unroll
  for (int ni = 0; ni < 4; ni++) {
    int r = wn + ni * 16 + m16;
#pragma unroll
    for (int h = 0; h < 2; h++)
      boff[ni][h] = (r * 8 + ((qd + h * 4) ^ (r & 7))) * 8;
  }

  f32x4 zero = {0.f, 0.f, 0.f, 0.f};
  f32x4 acc[4][4];
#pragma unroll
  for (int mi = 0; mi < 4; mi++)
#pragma unroll
    for (int ni = 0; ni < 4; ni++) acc[mi][ni] = zero;

  for (int k0 = 0; k0 < WW; k0 += BK) {
#pragma unroll
    for (int i2 = 0; i2 < 4; i2++) gload_lds16(gA[i2] + k0, ldsA[i2]);
#pragma unroll
    for (int i2 = 0; i2 < 4; i2++) gload_lds16(gB[i2] + k0, ldsB[i2]);
    __syncthreads();
#pragma unroll
    for (int h = 0; h < 2; h++) {
      bf16x8 af[4], bfr[4];
#pragma unroll
      for (int mi = 0; mi < 4; mi++) af[mi] = *(const bf16x8*)(As + aoff[mi][h]);
#pragma unroll
      for (int ni = 0; ni < 4; ni++) bfr[ni] = *(const bf16x8*)(Bs + boff[ni][h]);
#pragma unroll
      for (int mi = 0; mi < 4; mi++)
#pragma unroll
        for (int ni = 0; ni < 4; ni++)
          acc[mi][ni] = __builtin_amdgcn_mfma_f32_16x16x32_bf16(
              af[mi], bfr[ni], acc[mi][ni], 0, 0, 0);
    }
    __syncthreads();
  }

  // epilogue: raw y (routing weights applied in combine)
#pragma unroll
  for (int mi = 0; mi < 4; mi++) {
#pragma unroll
    for (int reg = 0; reg < 4; reg++) {
      int slot = mt * BM + wm + mi * 16 + qd * 4 + reg;
      if (slot < n_e) {
#pragma unroll
        for (int ni = 0; ni < 4; ni++) {
          int col = nt * BN + wn + ni * 16 + m16;
          y[((size_t)e * CAP + slot) * DD + col] = __float2bfloat16(acc[mi][ni][reg]);
        }
      }
    }
  }
}

// ---------------- combine: out[t] = w0*y[slot0] + w1*y[slot1] ----------------
__global__ __launch_bounds__(256) void combine_kernel(
    const __hip_bfloat16* __restrict__ y, const int* __restrict__ tslot,
    const float* __restrict__ wpair, float* __restrict__ out)
{
  int t = blockIdx.x;
  int c = threadIdx.x * 4;
  int s0 = tslot[2 * t], s1 = tslot[2 * t + 1];
  float w0 = wpair[2 * t], w1 = wpair[2 * t + 1];
  const unsigned short* yu = (const unsigned short*)y;
  ushort4 a = *(const ushort4*)(yu + (size_t)s0 * DD + c);
  ushort4 bq = *(const ushort4*)(yu + (size_t)s1 * DD + c);
  f32x4 o;
  o[0] = w0 * bf2f(a.x) + w1 * bf2f(bq.x);
  o[1] = w0 * bf2f(a.y) + w1 * bf2f(bq.y);
  o[2] = w0 * bf2f(a.z) + w1 * bf2f(bq.z);
  o[3] = w0 * bf2f(a.w) + w1 * bf2f(bq.w);
  *(f32x4*)(out + (size_t)t * DD + c) = o;
}

extern "C" void kernel_launch(void* const* d_in, const int* in_sizes, int n_in,
                              void* d_out, int out_size, void* d_ws, size_t ws_size,
                              hipStream_t stream)
{
  const float* x  = (const float*)d_in[0];
  const float* rw = (const float*)d_in[1];
  const float* w1 = (const float*)d_in[2];
  const float* w2 = (const float*)d_in[3];
  float* out = (float*)d_out;

  char* ws = (char*)d_ws;
  __hip_bfloat16* xb  = (__hip_bfloat16*)ws;  ws += (size_t)T_TOKENS * DD * 2;
  __hip_bfloat16* w1t = (__hip_bfloat16*)ws;  ws += (size_t)EE * WW * DD * 2;
  __hip_bfloat16* w2t = (__hip_bfloat16*)ws;  ws += (size_t)EE * DD * WW * 2;
  __hip_bfloat16* act = (__hip_bfloat16*)ws;  ws += (size_t)EE * CAP * WW * 2;
  __hip_bfloat16* y   = (__hip_bfloat16*)ws;  ws += (size_t)EE * CAP * DD * 2;
  int*   counts = (int*)ws;                   ws += 256;
  int*   idx    = (int*)ws;                   ws += (size_t)EE * CAP * 4;
  int*   sel    = (int*)ws;                   ws += (size_t)T_TOKENS * 4;
  int*   tslot  = (int*)ws;                   ws += (size_t)T_TOKENS * 8;
  float* wpair  = (float*)ws;                 ws += (size_t)T_TOKENS * 8;

  // pre: w1 transpose + router (sel/wpair only -- list build is deterministic,
  // contention-free, in build_lists below)
  pre_kernel<<<TR1_BLOCKS + T_TOKENS / 4, 256, 0, stream>>>(
      w1, x, rw, w1t, xb, sel, wpair);
  build_lists<<<1, 1024, 0, stream>>>(sel, counts, idx, tslot);
  // gemm1 + fused w2 transpose (w2t only needed by gemm2)
  gemm1_kernel<<<GEMM_BLOCKS + TR2_BLOCKS, 256, 0, stream>>>(
      xb, w1t, counts, idx, act, w2, w2t);
  gemm2_kernel<<<GEMM_BLOCKS, 256, 0, stream>>>(act, w2t, counts, y);
  combine_kernel<<<T_TOKENS, 256, 0, stream>>>(y, tslot, wpair, out);
}